// Round 3
// baseline (543.576 us; speedup 1.0000x reference)
//
#include <hip/hip_runtime.h>

#define BATCH 32
#define LSEQ  4096
#define HDIM  768            // 192 float4 per row
#define NEGV  (-1e30f)

// ---------------------------------------------------------------------------
// Kernel 1: per-row dual dot product. 32 lanes per row, 2 lane-groups per
// wave, 2 row-pairs unrolled per iteration (4 rows per wave-iter).
// W fragments: 6 float4 each of w1/w2 (48 VGPRs) -> ~120 VGPR total ->
// 4 waves/SIMD (16 waves/CU), 2x the R2 occupancy. 12 independent x-loads
// in flight per lane per iteration.
// ---------------------------------------------------------------------------
__global__ __launch_bounds__(512, 4) void st_kernel(const float* __restrict__ words,
                                                    const float* __restrict__ W,
                                                    float* __restrict__ s_buf,
                                                    float* __restrict__ t_buf,
                                                    int total_quads) {
    const int lane = threadIdx.x & 63;
    const int sub  = lane & 31;          // chunk index within row
    const int r    = lane >> 5;          // 0..1: which row of the pair
    const int wave_global = blockIdx.x * 8 + (threadIdx.x >> 6);
    const int total_waves = gridDim.x * 8;

    const float4* Wv = (const float4*)W;   // 384 float4: w1=[0,192), w2=[192,384)
    float4 a[6], b[6];
    #pragma unroll
    for (int j = 0; j < 6; ++j) {
        a[j] = Wv[sub + 32 * j];
        b[j] = Wv[192 + sub + 32 * j];
    }

    for (int q = wave_global; q < total_quads; q += total_waves) {
        const int row0 = q * 4 + r;          // rows q*4+r and q*4+2+r
        const int row1 = row0 + 2;
        const float4* wp0 = (const float4*)words + (size_t)row0 * (HDIM / 4);
        const float4* wp1 = (const float4*)words + (size_t)row1 * (HDIM / 4);

        float4 x0[6], x1[6];
        #pragma unroll
        for (int j = 0; j < 6; ++j) x0[j] = wp0[sub + 32 * j];
        #pragma unroll
        for (int j = 0; j < 6; ++j) x1[j] = wp1[sub + 32 * j];

        float s0 = 0.f, t0 = 0.f, s1 = 0.f, t1 = 0.f;
        #pragma unroll
        for (int j = 0; j < 6; ++j) {
            s0 += x0[j].x * a[j].x; s0 += x0[j].y * a[j].y; s0 += x0[j].z * a[j].z; s0 += x0[j].w * a[j].w;
            t0 += x0[j].x * b[j].x; t0 += x0[j].y * b[j].y; t0 += x0[j].z * b[j].z; t0 += x0[j].w * b[j].w;
            s1 += x1[j].x * a[j].x; s1 += x1[j].y * a[j].y; s1 += x1[j].z * a[j].z; s1 += x1[j].w * a[j].w;
            t1 += x1[j].x * b[j].x; t1 += x1[j].y * b[j].y; t1 += x1[j].z * b[j].z; t1 += x1[j].w * b[j].w;
        }
        #pragma unroll
        for (int off = 16; off > 0; off >>= 1) {
            s0 += __shfl_down(s0, off, 32);
            t0 += __shfl_down(t0, off, 32);
            s1 += __shfl_down(s1, off, 32);
            t1 += __shfl_down(t1, off, 32);
        }
        if (sub == 0) {
            s_buf[row0] = s0;  t_buf[row0] = t0;
            s_buf[row1] = s1;  t_buf[row1] = t1;
        }
    }
}

// ---------------------------------------------------------------------------
// Kernel 2: per-batch sliding-window max. out[b] = max(0, M + bias) where
// M = max over l, k in [1,5], l+k < L of (s[l] + t[l+k]).
// ---------------------------------------------------------------------------
__global__ __launch_bounds__(256) void max_kernel(const float* __restrict__ s_buf,
                                                  const float* __restrict__ t_buf,
                                                  const float* __restrict__ bias,
                                                  float* __restrict__ out) {
    const int b = blockIdx.x;
    const float* s = s_buf + (size_t)b * LSEQ;
    const float* t = t_buf + (size_t)b * LSEQ;

    float m = NEGV;
    for (int l = threadIdx.x; l < LSEQ; l += 256) {
        float tm = NEGV;
        #pragma unroll
        for (int k = 1; k <= 5; ++k) {
            if (l + k < LSEQ) tm = fmaxf(tm, t[l + k]);
        }
        m = fmaxf(m, s[l] + tm);
    }
    #pragma unroll
    for (int off = 32; off > 0; off >>= 1) {
        m = fmaxf(m, __shfl_down(m, off, 64));
    }
    __shared__ float red[4];
    if ((threadIdx.x & 63) == 0) red[threadIdx.x >> 6] = m;
    __syncthreads();
    if (threadIdx.x == 0) {
        float M = fmaxf(fmaxf(red[0], red[1]), fmaxf(red[2], red[3]));
        out[b] = fmaxf(0.f, M + bias[0]);
    }
}

extern "C" void kernel_launch(void* const* d_in, const int* in_sizes, int n_in,
                              void* d_out, int out_size, void* d_ws, size_t ws_size,
                              hipStream_t stream) {
    const float* words = (const float*)d_in[0];
    // d_in[1] = diff (unused by the reference)
    const float* W    = (const float*)d_in[2];
    const float* bias = (const float*)d_in[3];
    float* out = (float*)d_out;

    float* s_buf = (float*)d_ws;                 // BATCH*LSEQ floats
    float* t_buf = s_buf + BATCH * LSEQ;         // BATCH*LSEQ floats (1 MB total)

    const int total_quads = (BATCH * LSEQ) / 4;  // 32768 quads of 4 rows
    // 1024 blocks x 8 waves = 8192 waves -> 4 quads (16 rows) per wave
    st_kernel<<<1024, 512, 0, stream>>>(words, W, s_buf, t_buf, total_quads);
    max_kernel<<<BATCH, 256, 0, stream>>>(s_buf, t_buf, bias, out);
}